// Round 10
// baseline (686.629 us; speedup 1.0000x reference)
//
#include <hip/hip_runtime.h>

// ============================================================================
// train_model_27925877358676 — round 14: tail pipeline split.
//  r13 post-mortem: launch-gap model saturated; tail = 5 serial small
//  launches. Fixes: (1) r12's norm-GEMM (proven-correct) moved to its OWN
//  kernel (gemm_normdual) so its VGPR load can't contaminate gemm_dual.
//  (2) proj1/proj2 split into g1/g2 halves: proj1a rides gemm_tri
//  (xp2||div||proj1a), proj2a rides normdual. Tail chain now
//  reduce2 -> normdual -> proj1b -> proj2b -> final.
//  12 dispatches + 1 memset (was 13+1). ws ≈ 181 MB.
// ============================================================================

typedef unsigned short ushort;
typedef __attribute__((ext_vector_type(8))) short short8;     // 8 bf16
typedef __attribute__((ext_vector_type(4))) float float4v;    // 4 fp32 acc
typedef __attribute__((ext_vector_type(4))) float f32x4;
typedef __attribute__((ext_vector_type(2))) float f32x2;
typedef __attribute__((ext_vector_type(8))) unsigned short us8;
typedef __attribute__((ext_vector_type(4))) unsigned short us4;
typedef __attribute__((ext_vector_type(2))) unsigned short us2;

__device__ __forceinline__ ushort bf16_rne(float v) {
    unsigned u = __float_as_uint(v);
    u += 0x7fffu + ((u >> 16) & 1u);
    return (ushort)(u >> 16);
}
__device__ __forceinline__ float bf16_f32(ushort h) {
    return __uint_as_float((unsigned)h << 16);
}

// ---------------- workspace layout ----------------
// fp32/int region (element offsets)
constexpr long ZCNT0 = 0;          // int[8000] (zeroed by memset)
constexpr long ZCNT1 = 8000;       // int[2000]
constexpr long ELL0  = 10240;      // int[8000*64]
constexpr long ELL1  = 522240;     // int[2000*64]
constexpr long H1F   = 650240;     // f[8064*256]
constexpr long H2F   = 2714624;    // f[2048*256]
constexpr long DIVCF = 3238912;    // f[2048*512]
constexpr long PB2   = 4811776;    // f[4096*256]
constexpr long PART  = 5860352;    // f[4*2048*512] split-K partial slabs
constexpr long FEND  = 10054656;
// bf16 region (ushort offsets from uws)
constexpr long U_PPRB  = 0;         // [2048][8192]
constexpr long U_PPR2B = 16777216;  // [2048][2048]
constexpr long U_XTB   = 20971520;  // [512][8192]
constexpr long U_XPATB = 25165824;  // [512][2048]
constexpr long U_A0    = 26214400;  // [8064][1536] = [x | agg_hi | agg_lo]
constexpr long U_A1    = 38600704;  // [2048][1024]
constexpr long U_ESPL  = 40697856;  // [2048][512]
constexpr long U_XPS   = 41746432;  // [2048][1024]
constexpr long U_SPLT  = 43843584;  // [4096][512]
constexpr long U_TSPL  = 45940736;  // [4096][512]
constexpr long U_WC0   = 48037888;  // [256][1536]
constexpr long U_WC1   = 48431104;  // [256][1024]
constexpr long U_BD    = 48693248;  // [512][512]
constexpr long U_WAD   = 48955392;  // [512][1024]
constexpr long U_WBD   = 49479680;  // [256][1024]
constexpr long U_WP1D  = 49741824;  // [256][512]
constexpr long U_WP2D  = 49872896;  // [256][512]
constexpr long U_XB    = 50003968;  // [40000][512]
// end 70483968 ushorts = 141.0 MB

// ---------------------------------------------------------------------------
// GemmDesc + run_gemm.
// flags: bit0 relu, bit1 split-store, bit2 transposed-store,
//        bit3 XCD swizzle ((gx*gy)%8==0), bit4 split-K slab store.
// ---------------------------------------------------------------------------
struct GemmDesc {
    const ushort* A; const ushort* B;
    float* Cf; ushort* Cs; ushort* Ct;
    const float* bias;
    int K, lda, ldb, ldc;
    int ldso, nsplit, msplit, ldt;
    int gx, gy, kchunk;
    long slabsize;
    int flags;
};

__device__ __forceinline__ void run_gemm(const GemmDesc& d, int f,
                                         ushort* As, ushort* Bs)
{
    const int tid = threadIdx.x;
    const int lane = tid & 63, wave = tid >> 6;
    const int wm = (wave >> 1) * 64, wn = (wave & 1) * 64;
    const int lr = lane & 15, quad = lane >> 4;

    int per = d.gx * d.gy;
    int z = f / per;
    int rem = f - z * per;
    if (d.flags & 8) {
        int c = rem & 7, j = rem >> 3;
        rem = c * (per >> 3) + j;
    }
    int by = rem / d.gx, bx = rem - by * d.gx;
    const int bm = by * 128, bn = bx * 128;
    const int kbeg = z * d.kchunk;
    int kend = kbeg + d.kchunk; if (kend > d.K) kend = d.K;

    float4v acc[4][4] = {{{0.f, 0.f, 0.f, 0.f}}};

    for (int k0 = kbeg; k0 < kend; k0 += 128) {
#pragma unroll
        for (int issue = 0; issue < 8; ++issue) {
            int c = issue * 256 + tid;
            int r = c >> 4, p = c & 15;
            int kk = (p ^ (r & 15)) * 8;
            const ushort* ga = d.A + (long)(bm + r) * d.lda + k0 + kk;
            const ushort* gb = d.B + (long)(bn + r) * d.ldb + k0 + kk;
            __builtin_amdgcn_global_load_lds(
                (const __attribute__((address_space(1))) unsigned int*)ga,
                (__attribute__((address_space(3))) unsigned int*)&As[c * 8], 16, 0, 0);
            __builtin_amdgcn_global_load_lds(
                (const __attribute__((address_space(1))) unsigned int*)gb,
                (__attribute__((address_space(3))) unsigned int*)&Bs[c * 8], 16, 0, 0);
        }
        __syncthreads();

#pragma unroll
        for (int s = 0; s < 4; ++s) {
            short8 af[4], bf[4];
#pragma unroll
            for (int i = 0; i < 4; ++i) {
                int ra = wm + i * 16 + lr;
                af[i] = *(const short8*)&As[ra * 128 + (((s * 4 + quad) ^ (ra & 15)) * 8)];
                int rb = wn + i * 16 + lr;
                bf[i] = *(const short8*)&Bs[rb * 128 + (((s * 4 + quad) ^ (rb & 15)) * 8)];
            }
#pragma unroll
            for (int i = 0; i < 4; ++i)
#pragma unroll
                for (int j = 0; j < 4; ++j)
                    acc[i][j] = __builtin_amdgcn_mfma_f32_16x16x32_bf16(
                        af[i], bf[j], acc[i][j], 0, 0, 0);
        }
        __syncthreads();
    }

    if (d.flags & 16) {
        float* Cz = d.Cf + (long)z * d.slabsize;
#pragma unroll
        for (int i = 0; i < 4; ++i) {
            int row0 = bm + wm + i * 16 + quad * 4;
#pragma unroll
            for (int j = 0; j < 4; ++j) {
                int col = bn + wn + j * 16 + lr;
#pragma unroll
                for (int r = 0; r < 4; ++r)
                    Cz[(long)(row0 + r) * d.ldc + col] = acc[i][j][r];
            }
        }
        return;
    }

#pragma unroll
    for (int i = 0; i < 4; ++i) {
        int row0 = bm + wm + i * 16 + quad * 4;
#pragma unroll
        for (int j = 0; j < 4; ++j) {
            int col = bn + wn + j * 16 + lr;
            float bv = d.bias ? d.bias[col] : 0.f;
            us4 tp;
#pragma unroll
            for (int r = 0; r < 4; ++r) {
                int row = row0 + r;
                float v = acc[i][j][r] + bv;
                if (d.flags & 1) v = fmaxf(v, 0.f);
                if (d.Cf) d.Cf[(long)row * d.ldc + col] = v;
                if (d.Cs && row < d.msplit) {
                    if (d.flags & 2) {
                        ushort h = bf16_rne(v);
                        d.Cs[(long)row * d.ldso + col] = h;
                        d.Cs[(long)row * d.ldso + d.nsplit + col] = bf16_rne(v - bf16_f32(h));
                    } else {
                        d.Cs[(long)row * d.ldso + col] = bf16_rne(v);
                    }
                }
                if (d.flags & 4) tp[r] = bf16_rne(v);
            }
            if (d.flags & 4)
                *(us4*)&d.Ct[(long)col * d.ldt + row0] = tp;
        }
    }
}

// ---------------------------------------------------------------------------
// run_gemm_norm (r12-proven, now quarantined in its own kernel): job f owns
// rows [f*128, f*128+128) with FULL 256 cols (two col-tiles). Epilogue:
// v = acc + bias, per-row L2 norm via LDS atomics, writes g=v/nrm as
// [hi(256)|lo(256)] split to d.Cs. K = d.K.
// ---------------------------------------------------------------------------
__device__ __forceinline__ void run_gemm_norm(const GemmDesc& d, int f,
                                              ushort* As, ushort* Bs)
{
    const int tid = threadIdx.x;
    const int lane = tid & 63, wave = tid >> 6;
    const int wm = (wave >> 1) * 64, wn = (wave & 1) * 64;
    const int lr = lane & 15, quad = lane >> 4;
    const int bm = f * 128;

    float4v acc[2][4][4] = {{{{0.f, 0.f, 0.f, 0.f}}}};

#pragma unroll 2
    for (int tile = 0; tile < 2; ++tile) {
        for (int k0 = 0; k0 < d.K; k0 += 128) {
#pragma unroll
            for (int issue = 0; issue < 8; ++issue) {
                int c = issue * 256 + tid;
                int r = c >> 4, p = c & 15;
                int kk = (p ^ (r & 15)) * 8;
                const ushort* ga = d.A + (long)(bm + r) * d.lda + k0 + kk;
                const ushort* gb = d.B + (long)(tile * 128 + r) * d.ldb + k0 + kk;
                __builtin_amdgcn_global_load_lds(
                    (const __attribute__((address_space(1))) unsigned int*)ga,
                    (__attribute__((address_space(3))) unsigned int*)&As[c * 8], 16, 0, 0);
                __builtin_amdgcn_global_load_lds(
                    (const __attribute__((address_space(1))) unsigned int*)gb,
                    (__attribute__((address_space(3))) unsigned int*)&Bs[c * 8], 16, 0, 0);
            }
            __syncthreads();
#pragma unroll
            for (int s = 0; s < 4; ++s) {
                short8 af[4], bf[4];
#pragma unroll
                for (int i = 0; i < 4; ++i) {
                    int ra = wm + i * 16 + lr;
                    af[i] = *(const short8*)&As[ra * 128 + (((s * 4 + quad) ^ (ra & 15)) * 8)];
                    int rb = wn + i * 16 + lr;
                    bf[i] = *(const short8*)&Bs[rb * 128 + (((s * 4 + quad) ^ (rb & 15)) * 8)];
                }
#pragma unroll
                for (int i = 0; i < 4; ++i)
#pragma unroll
                    for (int j = 0; j < 4; ++j)
                        acc[tile][i][j] = __builtin_amdgcn_mfma_f32_16x16x32_bf16(
                            af[i], bf[j], acc[tile][i][j], 0, 0, 0);
            }
            __syncthreads();
        }
    }

    // ---- fused row L2-norm epilogue ----
    float* rs = (float*)As;             // reuse LDS
    if (tid < 128) rs[tid] = 0.f;
    __syncthreads();
#pragma unroll
    for (int i = 0; i < 4; ++i) {
#pragma unroll
        for (int r = 0; r < 4; ++r) {
            int rl = wm + i * 16 + quad * 4 + r;
            float p = 0.f;
#pragma unroll
            for (int j = 0; j < 4; ++j) {
                int c0 = wn + j * 16 + lr;
                float v0 = acc[0][i][j][r] + d.bias[c0];
                float v1 = acc[1][i][j][r] + d.bias[128 + c0];
                acc[0][i][j][r] = v0;
                acc[1][i][j][r] = v1;
                p += v0 * v0 + v1 * v1;
            }
            atomicAdd(&rs[rl], p);
        }
    }
    __syncthreads();
#pragma unroll
    for (int i = 0; i < 4; ++i) {
#pragma unroll
        for (int r = 0; r < 4; ++r) {
            int rl = wm + i * 16 + quad * 4 + r;
            float inv = 1.f / fmaxf(sqrtf(rs[rl]), 1e-12f);
            long ro = (long)(bm + rl) * 512;
#pragma unroll
            for (int j = 0; j < 4; ++j) {
                int c0 = wn + j * 16 + lr;
                float g0 = acc[0][i][j][r] * inv;
                float g1 = acc[1][i][j][r] * inv;
                ushort h0 = bf16_rne(g0), h1 = bf16_rne(g1);
                d.Cs[ro + c0] = h0;
                d.Cs[ro + 256 + c0] = bf16_rne(g0 - bf16_f32(h0));
                d.Cs[ro + 128 + c0] = h1;
                d.Cs[ro + 256 + 128 + c0] = bf16_rne(g1 - bf16_f32(h1));
            }
        }
    }
}

// ---- vectorized reduce: sum S slabs of [2048][512] f32 -> bf16 [hi|lo] ----
__device__ __forceinline__ void reduce4_body(
    const float* __restrict__ part, ushort* __restrict__ outs, long j, int S)
{
    if (j >= 262144) return;
    long i4 = j * 4;
    f32x4 s = {0.f, 0.f, 0.f, 0.f};
    for (int k = 0; k < S; ++k)
        s += *(const f32x4*)&part[(long)k * 1048576 + i4];
    int r = (int)(i4 >> 9), c = (int)(i4 & 511);
    us4 hi, lo;
#pragma unroll
    for (int q = 0; q < 4; ++q) {
        ushort h = bf16_rne(s[q]);
        hi[q] = h;
        lo[q] = bf16_rne(s[q] - bf16_f32(h));
    }
    *(us4*)&outs[(long)r * 1024 + c] = hi;
    *(us4*)&outs[(long)r * 1024 + 512 + c] = lo;
}

// ---------------------------------------------------------------------------
__global__ __launch_bounds__(256) void gemm_one(GemmDesc d)
{
    __shared__ ushort As[16384];
    __shared__ ushort Bs[16384];
    run_gemm(d, blockIdx.x, As, Bs);
}

__global__ __launch_bounds__(256) void gemm_dual(GemmDesc d0, int n0, GemmDesc d1)
{
    __shared__ ushort As[16384];
    __shared__ ushort Bs[16384];
    int f = blockIdx.x;
    if (f < n0) run_gemm(d0, f, As, Bs);
    else        run_gemm(d1, f - n0, As, Bs);
}

__global__ __launch_bounds__(256) void gemm_tri(
    GemmDesc d0, int n0, GemmDesc d1, int n1, GemmDesc d2)
{
    __shared__ ushort As[16384];
    __shared__ ushort Bs[16384];
    int f = blockIdx.x;
    if (f < n0)           run_gemm(d0, f, As, Bs);
    else if (f < n0 + n1) run_gemm(d1, f - n0, As, Bs);
    else                  run_gemm(d2, f - n0 - n1, As, Bs);
}

// norm (16 blocks) || proj2a (32 blocks) — register pressure quarantined here
__global__ __launch_bounds__(256) void gemm_normdual(
    GemmDesc dn, int n0, GemmDesc d1)
{
    __shared__ ushort As[16384];
    __shared__ ushort Bs[16384];
    int f = blockIdx.x;
    if (f < n0) run_gemm_norm(dn, f, As, Bs);
    else        run_gemm(d1, f - n0, As, Bs);
}

// standalone vectorized reduce (1024 blocks)
__global__ __launch_bounds__(256) void reduce_split(
    const float* __restrict__ part, ushort* __restrict__ outs, int S)
{
    reduce4_body(part, outs, (long)blockIdx.x * 256 + threadIdx.x, S);
}

// csr_agg1 (blocks [0,2048)) + reduce4 xp1 S=4 (blocks [2048,3072))
__global__ __launch_bounds__(256) void aggred(
    const float* __restrict__ h, const int* __restrict__ ell,
    const int* __restrict__ cnt, ushort* __restrict__ a1,
    const float* __restrict__ part, ushort* __restrict__ outs)
{
    __shared__ float pl[4][256];
    int b = blockIdx.x, t = threadIdx.x;
    if (b >= 2048) {
        reduce4_body(part, outs, (long)(b - 2048) * 256 + t, 4);
        return;
    }
    int d = b;
    int w = t >> 6, lane = t & 63;
    int k = (d < 2000) ? min(cnt[d], 64) : 0;
    f32x4 s = {0.f, 0.f, 0.f, 0.f};
    int co = lane * 4;
    int j = w;
    for (; j + 12 < k; j += 16) {
        int e0 = ell[d + 2000 * j],        e1 = ell[d + 2000 * (j + 4)];
        int e2 = ell[d + 2000 * (j + 8)],  e3 = ell[d + 2000 * (j + 12)];
        f32x4 v0 = *(const f32x4*)&h[(long)e0 * 256 + co];
        f32x4 v1 = *(const f32x4*)&h[(long)e1 * 256 + co];
        f32x4 v2 = *(const f32x4*)&h[(long)e2 * 256 + co];
        f32x4 v3 = *(const f32x4*)&h[(long)e3 * 256 + co];
        s += v0; s += v1; s += v2; s += v3;
    }
    for (; j < k; j += 4)
        s += *(const f32x4*)&h[(long)ell[d + 2000 * j] * 256 + co];
#pragma unroll
    for (int q = 0; q < 4; ++q) pl[w][co + q] = s[q];
    __syncthreads();
    float inv = 1.f / fmaxf((float)k, 1.f);
    float a = (pl[0][t] + pl[1][t] + pl[2][t] + pl[3][t]) * inv;
    ushort hi = bf16_rne(a);
    long ro = (long)d * 1024;
    a1[ro + 512 + t] = hi;
    a1[ro + 768 + t] = bf16_rne(a - bf16_f32(hi));
}

// ---------------------------------------------------------------------------
// prep megakernel + fused ELL build (cnt pre-zeroed by memset).
// ---------------------------------------------------------------------------
__global__ __launch_bounds__(256) void prep(
    const float* __restrict__ ppr, const float* __restrict__ x,
    const float* __restrict__ Wr0, const float* __restrict__ Wl0,
    const float* __restrict__ Wr1, const float* __restrict__ Wl1,
    const float* __restrict__ W1,  const float* __restrict__ W2,
    const float* __restrict__ Wa,  const float* __restrict__ Wb,
    const float* __restrict__ Wp1, const float* __restrict__ Wp2,
    const int* __restrict__ src0, const int* __restrict__ dst0,
    const int* __restrict__ src1, const int* __restrict__ dst1,
    int E0, int E1,
    ushort* __restrict__ uws, int* __restrict__ iws, float* __restrict__ outloss)
{
    __shared__ float tsm[32][33];
    int b = blockIdx.x, t = threadIdx.x;
    int nEll = (E0 + E1 + 255) >> 8;

    if (b < nEll) {                         // ---- ELL bucket build ----
        int e = b * 256 + t;
        if (e < E0) {
            int d = dst0[e];
            int r = atomicAdd(&iws[ZCNT0 + d], 1);
            if (r < 64) iws[ELL0 + d + 8000 * r] = src0[e];
        } else if (e < E0 + E1) {
            int e1 = e - E0;
            int d = dst1[e1];
            int r = atomicAdd(&iws[ZCNT1 + d], 1);
            if (r < 64) iws[ELL1 + d + 2000 * r] = src1[e1];
        }
        return;
    }
    int b1 = b - nEll;
    if (b1 == 0) {                          // ---- zero loss ----
        if (t == 0) outloss[0] = 0.f;
        return;
    }
    b1 -= 1;
    if (b1 < 256) {                         // ---- pack weights ----
        int b2 = b1;
        int sec = b2 >> 5;
        const float *sa, *sb = nullptr; long dstoff; int N, KA, dA, KB = 0, dB = 0;
        switch (sec) {
            case 0: sa = Wr0; KA = 512; dA = 1; sb = Wl0; KB = 512; dB = 2;
                    dstoff = U_WC0; N = 256; break;
            case 1: sa = Wr1; KA = 256; dA = 2; sb = Wl1; KB = 256; dB = 2;
                    dstoff = U_WC1; N = 256; break;
            case 2: sa = W1;  KA = 256; dA = 2; dstoff = U_BD;          N = 256; break;
            case 3: sa = W2;  KA = 256; dA = 2; dstoff = U_BD + 131072; N = 256; break;
            case 4: sa = Wa;  KA = 512; dA = 2; dstoff = U_WAD;  N = 512; break;
            case 5: sa = Wb;  KA = 512; dA = 2; dstoff = U_WBD;  N = 256; break;
            case 6: sa = Wp1; KA = 256; dA = 2; dstoff = U_WP1D; N = 256; break;
            default: sa = Wp2; KA = 256; dA = 2; dstoff = U_WP2D; N = 256; break;
        }
        int kd = KA * dA + KB * dB;
        long totv = (long)N * kd / 2;
        for (long v = (long)(b2 & 31) * 256 + t; v < totv; v += 8192) {
            long idx = v * 2;
            int n = (int)(idx / kd), rem = (int)(idx % kd);
            f32x2 val;
            if (rem < KA * dA) {
                int sc = rem % KA;
                val = *(const f32x2*)&sa[(long)n * KA + sc];
            } else {
                int sc = (rem - KA * dA) % KB;
                val = *(const f32x2*)&sb[(long)n * KB + sc];
            }
            us2 o; o[0] = bf16_rne(val[0]); o[1] = bf16_rne(val[1]);
            *(us2*)&uws[dstoff + idx] = o;
        }
        return;
    }
    b1 -= 256;
    if (b1 < 8192) {                        // ---- ppr conversion ----
        int r = b1 >> 2, q = b1 & 3;
        bool live = r < 2000;
        const float* row = ppr + (long)r * 8000;
        int cbeg = q * 2048;
#pragma unroll
        for (int pass = 0; pass < 2; ++pass) {
            int c = cbeg + pass * 1024 + t * 4;
            f32x4 v = {0.f, 0.f, 0.f, 0.f};
            if (live && c < 8000) v = *(const f32x4*)(row + c);
            us4 u;
            u[0] = bf16_rne(v[0]); u[1] = bf16_rne(v[1]);
            u[2] = bf16_rne(v[2]); u[3] = bf16_rne(v[3]);
            *(us4*)&uws[U_PPRB + (long)r * 8192 + c] = u;
            if (c < 2048) {
                us4 w = u;
                if (c >= 2000) { w[0] = 0; w[1] = 0; w[2] = 0; w[3] = 0; }
                *(us4*)&uws[U_PPR2B + (long)r * 2048 + c] = w;
            }
        }
        return;
    }
    b1 -= 8192;
    if (b1 < 4096) {                        // ---- transpose x -> XTB ----
        int c0 = (b1 & 15) * 32, r0 = (b1 >> 4) * 32;
        int tx = t & 31, ty = t >> 5;
#pragma unroll
        for (int k = 0; k < 32; k += 8) {
            int r = r0 + ty + k;
            tsm[ty + k][tx] = (r < 8000) ? x[(long)r * 512 + c0 + tx] : 0.f;
        }
        __syncthreads();
#pragma unroll
        for (int k = 0; k < 32; k += 8) {
            int c = c0 + ty + k;
            uws[U_XTB + (long)c * 8192 + r0 + tx] = bf16_rne(tsm[tx][ty + k]);
        }
        return;
    }
    b1 -= 4096;
    {                                       // ---- x row pass -> XB + A0 ----
        long vi = (long)b1 * 256 + t;
        for (; vi < 5120000; vi += 327680) {
            long gidx = vi * 4;
            f32x4 v = *(const f32x4*)&x[gidx];
            us4 u;
            u[0] = bf16_rne(v[0]); u[1] = bf16_rne(v[1]);
            u[2] = bf16_rne(v[2]); u[3] = bf16_rne(v[3]);
            *(us4*)&uws[U_XB + gidx] = u;
            long row = gidx >> 9;
            if (row < 8064) {
                int col = (int)(gidx & 511);
                *(us4*)&uws[U_A0 + row * 1536 + col] = u;
            }
        }
    }
}

// ---------------------------------------------------------------------------
// layer-0 gather-mean from bf16 XB, ELL layout
// ---------------------------------------------------------------------------
__global__ __launch_bounds__(256) void csr_agg0(
    const ushort* __restrict__ xb, const int* __restrict__ ell,
    const int* __restrict__ cnt, ushort* __restrict__ a0)
{
    __shared__ float part[4][512];
    int d = blockIdx.x, t = threadIdx.x;
    int w = t >> 6, lane = t & 63;
    int k = (d < 8000) ? min(cnt[d], 64) : 0;
    float s[8] = {0.f, 0.f, 0.f, 0.f, 0.f, 0.f, 0.f, 0.f};
    int co = lane * 8;
    int j = w;
    for (; j + 12 < k; j += 16) {
        int e0 = ell[d + 8000 * j],        e1 = ell[d + 8000 * (j + 4)];
        int e2 = ell[d + 8000 * (j + 8)],  e3 = ell[d + 8000 * (j + 12)];
        us8 v0 = *(const us8*)&xb[(long)e0 * 512 + co];
        us8 v1 = *(const us8*)&xb[(long)e1 * 512 + co];
        us8 v2 = *(const us8*)&xb[(long)e2 * 512 + co];
        us8 v3 = *(const us8*)&xb[(long)e3 * 512 + co];
#pragma unroll
        for (int q = 0; q < 8; ++q)
            s[q] += bf16_f32(v0[q]) + bf16_f32(v1[q]) +
                    bf16_f32(v2[q]) + bf16_f32(v3[q]);
    }
    for (; j < k; j += 4) {
        us8 v = *(const us8*)&xb[(long)ell[d + 8000 * j] * 512 + co];
#pragma unroll
        for (int q = 0; q < 8; ++q) s[q] += bf16_f32(v[q]);
    }
#pragma unroll
    for (int q = 0; q < 8; ++q) part[w][co + q] = s[q];
    __syncthreads();
    float inv = 1.f / fmaxf((float)k, 1.f);
    long ro = (long)d * 1536;
#pragma unroll
    for (int h = 0; h < 2; ++h) {
        int c = 2 * t + h;
        float a = (part[0][c] + part[1][c] + part[2][c] + part[3][c]) * inv;
        ushort hi = bf16_rne(a);
        a0[ro + 512 + c] = hi;
        a0[ro + 1024 + c] = bf16_rne(a - bf16_f32(hi));
    }
}

// rowcombo1: logsoftmax + l2n + splits on H2 -> ESPL, SPLT[0:2048)
__global__ __launch_bounds__(256) void rowcombo1(
    const float* __restrict__ h2, ushort* __restrict__ espl,
    ushort* __restrict__ splt)
{
    __shared__ float red[256];
    int i = blockIdx.x, t = threadIdx.x;
    float v = h2[(long)i * 256 + t];
    red[t] = v;
    __syncthreads();
    for (int s = 128; s > 0; s >>= 1) {
        if (t < s) red[t] = fmaxf(red[t], red[t + s]);
        __syncthreads();
    }
    float m = red[0];
    __syncthreads();
    float e = expf(v - m);
    red[t] = e;
    __syncthreads();
    for (int s = 128; s > 0; s >>= 1) {
        if (t < s) red[t] += red[t + s];
        __syncthreads();
    }
    float eb = v - (m + logf(red[0]));
    ushort hh = bf16_rne(eb);
    espl[(long)i * 512 + t] = hh;
    espl[(long)i * 512 + 256 + t] = bf16_rne(eb - bf16_f32(hh));
    __syncthreads();
    red[t] = eb * eb;
    __syncthreads();
    for (int s = 128; s > 0; s >>= 1) {
        if (t < s) red[t] += red[t + s];
        __syncthreads();
    }
    float g = eb / fmaxf(sqrtf(red[0]), 1e-12f);
    ushort gh = bf16_rne(g);
    splt[(long)i * 512 + t] = gh;
    splt[(long)i * 512 + 256 + t] = bf16_rne(g - bf16_f32(gh));
}

// ---------------------------------------------------------------------------
// final_combo: blocks [0,4096) clf (8-way dot) -> logits;
//              blocks [4096,6096) div_rows -> atomicAdd loss.
// ---------------------------------------------------------------------------
__global__ __launch_bounds__(256) void final_combo(
    const float* __restrict__ p, const float* __restrict__ Wc1,
    const float* __restrict__ bc1, const float* __restrict__ Wc2,
    const float* __restrict__ bc2, float* __restrict__ out,
    const float* __restrict__ divc, float scale)
{
    __shared__ float v[256];
    __shared__ float ps[8][33];
    __shared__ float hsum[32];
    __shared__ float r2[256];
    int b = blockIdx.x, t = threadIdx.x;
    if (b >= 4096) {
        int i = b - 4096;
        float a = divc[(long)i * 512 + t], bb = divc[(long)i * 512 + 256 + t];
        v[t] = a * a;
        r2[t] = bb * bb;
        __syncthreads();
        for (int s = 128; s > 0; s >>= 1) {
            if (t < s) { v[t] += v[t + s]; r2[t] += r2[t + s]; }
            __syncthreads();
        }
        float na = fmaxf(sqrtf(v[0]), 1e-12f);
        float nb = fmaxf(sqrtf(r2[0]), 1e-12f);
        __syncthreads();
        float d = a / na - bb / nb;
        v[t] = d * d;
        __syncthreads();
        for (int s = 128; s > 0; s >>= 1) {
            if (t < s) v[t] += v[t + s];
            __syncthreads();
        }
        if (t == 0) atomicAdd(&out[4000], v[0] * scale);
        return;
    }
    int half = b >> 11, i = b & 2047;
    if (i >= 2000) return;
    v[t] = p[(long)b * 256 + t];
    __syncthreads();
    int o = t & 31, ch = t >> 5;
    const float* w = Wc1 + (long)o * 256 + ch * 32;
    const float* vv = v + ch * 32;
    float s = 0.f;
#pragma unroll
    for (int k2 = 0; k2 < 32; ++k2) s += vv[k2] * w[k2];
    ps[ch][o] = s;
    __syncthreads();
    if (t < 32) {
        float a = bc1[t];
#pragma unroll
        for (int c = 0; c < 8; ++c) a += ps[c][t];
        a = fmaxf(a, 0.f);
        hsum[t] = a * Wc2[t];
    }
    __syncthreads();
    if (t == 0) {
        float s2 = bc2[0];
        for (int k2 = 0; k2 < 32; ++k2) s2 += hsum[k2];
        out[(long)i * 2 + half] = s2;
    }
}

// ---------------------------------------------------------------------------
extern "C" void kernel_launch(void* const* d_in, const int* in_sizes, int n_in,
                              void* d_out, int out_size, void* d_ws, size_t ws_size,
                              hipStream_t stream)
{
    constexpr int N2 = 2000;

    const float* x   = (const float*)d_in[0];
    const float* ppr = (const float*)d_in[1];
    const int* src0  = (const int*)d_in[2];
    const int* dst0  = (const int*)d_in[3];
    const int* src1  = (const int*)d_in[4];
    const int* dst1  = (const int*)d_in[5];
    const float* Wl0 = (const float*)d_in[8];
    const float* bl0 = (const float*)d_in[9];
    const float* Wr0 = (const float*)d_in[10];
    const float* Wl1 = (const float*)d_in[11];
    const float* bl1 = (const float*)d_in[12];
    const float* Wr1 = (const float*)d_in[13];
    const float* Wa  = (const float*)d_in[14];
    const float* ba  = (const float*)d_in[15];
    const float* Wb  = (const float*)d_in[16];
    const float* bb  = (const float*)d_in[17];
    const float* W1  = (const float*)d_in[18];
    const float* W2  = (const float*)d_in[19];
    const float* Wp1 = (const float*)d_in[20];
    const float* bp1 = (const float*)d_in[21];
    const float* Wp2 = (const float*)d_in[22];
    const float* bp2 = (const float*)d_in[23];
    const float* Wc1 = (const float*)d_in[24];
    const float* bc1 = (const float*)d_in[25];
    const float* Wc2 = (const float*)d_in[26];
    const float* bc2 = (const float*)d_in[27];

    const int E0 = in_sizes[2];
    const int E1 = in_sizes[4];

    float* out = (float*)d_out;              // [2000,2] logits + [1] loss
    float* ws  = (float*)d_ws;
    int*   iws = (int*)d_ws;
    ushort* uws = (ushort*)((char*)d_ws + FEND * sizeof(float));

    GemmDesc z{};

    // 0. zero ELL counters (stream-ordered before prep)
    hipMemsetAsync(iws, 0, 10240 * sizeof(int), stream);

    // 1. prep + ELL build
    int nEll = (E0 + E1 + 255) / 256;
    int prepGrid = nEll + 1 + 256 + 8192 + 4096 + 1280;
    prep<<<prepGrid, 256, 0, stream>>>(ppr, x, Wr0, Wl0, Wr1, Wl1, W1, W2,
                                       Wa, Wb, Wp1, Wp2,
                                       src0, dst0, src1, dst1, E0, E1,
                                       uws, iws, out + (long)N2 * 2);

    // 2. layer-0 gather-mean
    csr_agg0<<<8064, 256, 0, stream>>>(uws + U_XB, iws + ELL0, iws + ZCNT0,
                                       uws + U_A0);

    // 3. xp1 split-K (256) || H1 (126)
    GemmDesc dxp1 = z;
    dxp1.A = uws + U_PPRB; dxp1.B = uws + U_XTB; dxp1.Cf = ws + PART;
    dxp1.K = 8192; dxp1.lda = 8192; dxp1.ldb = 8192; dxp1.ldc = 512;
    dxp1.gx = 4; dxp1.gy = 16; dxp1.kchunk = 2048; dxp1.slabsize = 1048576;
    dxp1.flags = 16 | 8;
    GemmDesc dh1 = z;
    dh1.A = uws + U_A0; dh1.B = uws + U_WC0; dh1.Cf = ws + H1F;
    dh1.Cs = uws + U_A1; dh1.bias = bl0;
    dh1.K = 1536; dh1.lda = 1536; dh1.ldb = 1536; dh1.ldc = 256;
    dh1.ldso = 1024; dh1.nsplit = 256; dh1.msplit = 2048;
    dh1.gx = 2; dh1.gy = 63; dh1.kchunk = 1536; dh1.flags = 3;
    gemm_dual<<<382, 256, 0, stream>>>(dxp1, 256, dh1);

    // 4. csr_agg1 (2048) || reduce4 xp1 (1024)
    aggred<<<3072, 256, 0, stream>>>(ws + H1F, iws + ELL1, iws + ZCNT1,
                                     uws + U_A1, ws + PART, uws + U_XPS);

    // 5. xpa (64) || H2 (32)
    GemmDesc dxpa = z;
    dxpa.A = uws + U_XPS; dxpa.B = uws + U_WAD; dxpa.Ct = uws + U_XPATB;
    dxpa.bias = ba;
    dxpa.K = 1024; dxpa.lda = 1024; dxpa.ldb = 1024; dxpa.ldt = 2048;
    dxpa.gx = 4; dxpa.gy = 16; dxpa.kchunk = 1024; dxpa.flags = 1 | 4 | 8;
    GemmDesc dh2 = z;
    dh2.A = uws + U_A1; dh2.B = uws + U_WC1; dh2.Cf = ws + H2F; dh2.bias = bl1;
    dh2.K = 1024; dh2.lda = 1024; dh2.ldb = 1024; dh2.ldc = 256;
    dh2.gx = 2; dh2.gy = 16; dh2.kchunk = 1024; dh2.flags = 8;
    gemm_dual<<<96, 256, 0, stream>>>(dxpa, 64, dh2);

    // 6. rowcombo1 standalone (full occupancy)
    rowcombo1<<<N2, 256, 0, stream>>>(ws + H2F, uws + U_ESPL, uws + U_SPLT);

    // 7. xp2 split-K (128) || div GEMM (64) || proj1a (32, g1 rows)
    GemmDesc dxp2 = z;
    dxp2.A = uws + U_PPR2B; dxp2.B = uws + U_XPATB; dxp2.Cf = ws + PART;
    dxp2.K = 2048; dxp2.lda = 2048; dxp2.ldb = 2048; dxp2.ldc = 512;
    dxp2.gx = 4; dxp2.gy = 16; dxp2.kchunk = 1024; dxp2.slabsize = 1048576;
    dxp2.flags = 16 | 8;
    GemmDesc ddiv = z;
    ddiv.A = uws + U_ESPL; ddiv.B = uws + U_BD; ddiv.Cf = ws + DIVCF;
    ddiv.K = 512; ddiv.lda = 512; ddiv.ldb = 512; ddiv.ldc = 512;
    ddiv.gx = 4; ddiv.gy = 16; ddiv.kchunk = 512; ddiv.flags = 8;
    GemmDesc dp1a = z;
    dp1a.A = uws + U_SPLT; dp1a.B = uws + U_WP1D; dp1a.Cs = uws + U_TSPL;
    dp1a.bias = bp1;
    dp1a.K = 512; dp1a.lda = 512; dp1a.ldb = 512;
    dp1a.ldso = 512; dp1a.nsplit = 256; dp1a.msplit = 2048;
    dp1a.gx = 2; dp1a.gy = 16; dp1a.kchunk = 512; dp1a.flags = 1 | 2 | 8;
    gemm_tri<<<224, 256, 0, stream>>>(dxp2, 128, ddiv, 64, dp1a);

    // 8. reduce4 xp2 standalone (1024 blocks)
    reduce_split<<<1024, 256, 0, stream>>>(ws + PART, uws + U_XPS, 2);

    // 9. norm (16: xpb+l2n+split -> SPLT g2 rows) || proj2a (32)
    GemmDesc dnorm = z;
    dnorm.A = uws + U_XPS; dnorm.B = uws + U_WBD;
    dnorm.Cs = uws + U_SPLT + (long)2048 * 512;
    dnorm.bias = bb;
    dnorm.K = 1024; dnorm.lda = 1024; dnorm.ldb = 1024;
    GemmDesc dp2a = z;
    dp2a.A = uws + U_TSPL; dp2a.B = uws + U_WP2D; dp2a.Cf = ws + PB2;
    dp2a.bias = bp2;
    dp2a.K = 512; dp2a.lda = 512; dp2a.ldb = 512; dp2a.ldc = 256;
    dp2a.gx = 2; dp2a.gy = 16; dp2a.kchunk = 512; dp2a.flags = 8;
    gemm_normdual<<<48, 256, 0, stream>>>(dnorm, 16, dp2a);

    // 10. proj1b (32, g2 rows)
    GemmDesc dp1b = dp1a;
    dp1b.A = uws + U_SPLT + (long)2048 * 512;
    dp1b.Cs = uws + U_TSPL + (long)2048 * 512;
    gemm_one<<<32, 256, 0, stream>>>(dp1b);

    // 11. proj2b (32)
    GemmDesc dp2b = dp2a;
    dp2b.A = uws + U_TSPL + (long)2048 * 512;
    dp2b.Cf = ws + PB2 + (long)2048 * 256;
    gemm_one<<<32, 256, 0, stream>>>(dp2b);

    // 12. clf + div_rows -> out
    final_combo<<<6096, 256, 0, stream>>>(ws + PB2, Wc1, bc1, Wc2, bc2, out,
                                          ws + DIVCF, 1.0f / N2);
}

// Round 11
// 669.993 us; speedup vs baseline: 1.0248x; 1.0248x over previous
//
#include <hip/hip_runtime.h>

// ============================================================================
// train_model_27925877358676 — round 15: revert to r13 (2x measured 672us)
//  + one proven-pattern micro-fusion: div_rows rides the reduce2 launch
//  (aux||aux small-LDS, same mechanism as aggred/auxdual2); final_combo
//  becomes clf-only. r14's norm-kernel + proj-split both reverted (each
//  halved parallelism or added launches; net +14us).
//  13 dispatches + 1 memset. ws ≈ 181 MB.
// ============================================================================

typedef unsigned short ushort;
typedef __attribute__((ext_vector_type(8))) short short8;     // 8 bf16
typedef __attribute__((ext_vector_type(4))) float float4v;    // 4 fp32 acc
typedef __attribute__((ext_vector_type(4))) float f32x4;
typedef __attribute__((ext_vector_type(2))) float f32x2;
typedef __attribute__((ext_vector_type(8))) unsigned short us8;
typedef __attribute__((ext_vector_type(4))) unsigned short us4;
typedef __attribute__((ext_vector_type(2))) unsigned short us2;

__device__ __forceinline__ ushort bf16_rne(float v) {
    unsigned u = __float_as_uint(v);
    u += 0x7fffu + ((u >> 16) & 1u);
    return (ushort)(u >> 16);
}
__device__ __forceinline__ float bf16_f32(ushort h) {
    return __uint_as_float((unsigned)h << 16);
}

// ---------------- workspace layout ----------------
// fp32/int region (element offsets)
constexpr long ZCNT0 = 0;          // int[8000] (zeroed by memset)
constexpr long ZCNT1 = 8000;       // int[2000]
constexpr long ELL0  = 10240;      // int[8000*64]
constexpr long ELL1  = 522240;     // int[2000*64]
constexpr long H1F   = 650240;     // f[8064*256]
constexpr long H2F   = 2714624;    // f[2048*256]
constexpr long DIVCF = 3238912;    // f[2048*512]
constexpr long XPBF  = 4287488;    // f[2048*256]
constexpr long PB2   = 4811776;    // f[4096*256]
constexpr long PART  = 5860352;    // f[4*2048*512] split-K partial slabs
constexpr long FEND  = 10054656;
// bf16 region (ushort offsets from uws)
constexpr long U_PPRB  = 0;         // [2048][8192]
constexpr long U_PPR2B = 16777216;  // [2048][2048]
constexpr long U_XTB   = 20971520;  // [512][8192]
constexpr long U_XPATB = 25165824;  // [512][2048]
constexpr long U_A0    = 26214400;  // [8064][1536] = [x | agg_hi | agg_lo]
constexpr long U_A1    = 38600704;  // [2048][1024]
constexpr long U_ESPL  = 40697856;  // [2048][512]
constexpr long U_XPS   = 41746432;  // [2048][1024]
constexpr long U_SPLT  = 43843584;  // [4096][512]
constexpr long U_TSPL  = 45940736;  // [4096][512]
constexpr long U_WC0   = 48037888;  // [256][1536]
constexpr long U_WC1   = 48431104;  // [256][1024]
constexpr long U_BD    = 48693248;  // [512][512]
constexpr long U_WAD   = 48955392;  // [512][1024]
constexpr long U_WBD   = 49479680;  // [256][1024]
constexpr long U_WP1D  = 49741824;  // [256][512]
constexpr long U_WP2D  = 49872896;  // [256][512]
constexpr long U_XB    = 50003968;  // [40000][512]
// end 70483968 ushorts = 141.0 MB

// ---------------------------------------------------------------------------
// GemmDesc + run_gemm.
// flags: bit0 relu, bit1 split-store, bit2 transposed-store,
//        bit3 XCD swizzle ((gx*gy)%8==0), bit4 split-K slab store.
// ---------------------------------------------------------------------------
struct GemmDesc {
    const ushort* A; const ushort* B;
    float* Cf; ushort* Cs; ushort* Ct;
    const float* bias;
    int K, lda, ldb, ldc;
    int ldso, nsplit, msplit, ldt;
    int gx, gy, kchunk;
    long slabsize;
    int flags;
};

__device__ __forceinline__ void run_gemm(const GemmDesc& d, int f,
                                         ushort* As, ushort* Bs)
{
    const int tid = threadIdx.x;
    const int lane = tid & 63, wave = tid >> 6;
    const int wm = (wave >> 1) * 64, wn = (wave & 1) * 64;
    const int lr = lane & 15, quad = lane >> 4;

    int per = d.gx * d.gy;
    int z = f / per;
    int rem = f - z * per;
    if (d.flags & 8) {
        int c = rem & 7, j = rem >> 3;
        rem = c * (per >> 3) + j;
    }
    int by = rem / d.gx, bx = rem - by * d.gx;
    const int bm = by * 128, bn = bx * 128;
    const int kbeg = z * d.kchunk;
    int kend = kbeg + d.kchunk; if (kend > d.K) kend = d.K;

    float4v acc[4][4] = {{{0.f, 0.f, 0.f, 0.f}}};

    for (int k0 = kbeg; k0 < kend; k0 += 128) {
#pragma unroll
        for (int issue = 0; issue < 8; ++issue) {
            int c = issue * 256 + tid;
            int r = c >> 4, p = c & 15;
            int kk = (p ^ (r & 15)) * 8;
            const ushort* ga = d.A + (long)(bm + r) * d.lda + k0 + kk;
            const ushort* gb = d.B + (long)(bn + r) * d.ldb + k0 + kk;
            __builtin_amdgcn_global_load_lds(
                (const __attribute__((address_space(1))) unsigned int*)ga,
                (__attribute__((address_space(3))) unsigned int*)&As[c * 8], 16, 0, 0);
            __builtin_amdgcn_global_load_lds(
                (const __attribute__((address_space(1))) unsigned int*)gb,
                (__attribute__((address_space(3))) unsigned int*)&Bs[c * 8], 16, 0, 0);
        }
        __syncthreads();

#pragma unroll
        for (int s = 0; s < 4; ++s) {
            short8 af[4], bf[4];
#pragma unroll
            for (int i = 0; i < 4; ++i) {
                int ra = wm + i * 16 + lr;
                af[i] = *(const short8*)&As[ra * 128 + (((s * 4 + quad) ^ (ra & 15)) * 8)];
                int rb = wn + i * 16 + lr;
                bf[i] = *(const short8*)&Bs[rb * 128 + (((s * 4 + quad) ^ (rb & 15)) * 8)];
            }
#pragma unroll
            for (int i = 0; i < 4; ++i)
#pragma unroll
                for (int j = 0; j < 4; ++j)
                    acc[i][j] = __builtin_amdgcn_mfma_f32_16x16x32_bf16(
                        af[i], bf[j], acc[i][j], 0, 0, 0);
        }
        __syncthreads();
    }

    if (d.flags & 16) {
        float* Cz = d.Cf + (long)z * d.slabsize;
#pragma unroll
        for (int i = 0; i < 4; ++i) {
            int row0 = bm + wm + i * 16 + quad * 4;
#pragma unroll
            for (int j = 0; j < 4; ++j) {
                int col = bn + wn + j * 16 + lr;
#pragma unroll
                for (int r = 0; r < 4; ++r)
                    Cz[(long)(row0 + r) * d.ldc + col] = acc[i][j][r];
            }
        }
        return;
    }

#pragma unroll
    for (int i = 0; i < 4; ++i) {
        int row0 = bm + wm + i * 16 + quad * 4;
#pragma unroll
        for (int j = 0; j < 4; ++j) {
            int col = bn + wn + j * 16 + lr;
            float bv = d.bias ? d.bias[col] : 0.f;
            us4 tp;
#pragma unroll
            for (int r = 0; r < 4; ++r) {
                int row = row0 + r;
                float v = acc[i][j][r] + bv;
                if (d.flags & 1) v = fmaxf(v, 0.f);
                if (d.Cf) d.Cf[(long)row * d.ldc + col] = v;
                if (d.Cs && row < d.msplit) {
                    if (d.flags & 2) {
                        ushort h = bf16_rne(v);
                        d.Cs[(long)row * d.ldso + col] = h;
                        d.Cs[(long)row * d.ldso + d.nsplit + col] = bf16_rne(v - bf16_f32(h));
                    } else {
                        d.Cs[(long)row * d.ldso + col] = bf16_rne(v);
                    }
                }
                if (d.flags & 4) tp[r] = bf16_rne(v);
            }
            if (d.flags & 4)
                *(us4*)&d.Ct[(long)col * d.ldt + row0] = tp;
        }
    }
}

// ---- vectorized reduce: sum S slabs of [2048][512] f32 -> bf16 [hi|lo] ----
__device__ __forceinline__ void reduce4_body(
    const float* __restrict__ part, ushort* __restrict__ outs, long j, int S)
{
    if (j >= 262144) return;
    long i4 = j * 4;
    f32x4 s = {0.f, 0.f, 0.f, 0.f};
    for (int k = 0; k < S; ++k)
        s += *(const f32x4*)&part[(long)k * 1048576 + i4];
    int r = (int)(i4 >> 9), c = (int)(i4 & 511);
    us4 hi, lo;
#pragma unroll
    for (int q = 0; q < 4; ++q) {
        ushort h = bf16_rne(s[q]);
        hi[q] = h;
        lo[q] = bf16_rne(s[q] - bf16_f32(h));
    }
    *(us4*)&outs[(long)r * 1024 + c] = hi;
    *(us4*)&outs[(long)r * 1024 + 512 + c] = lo;
}

// ---------------------------------------------------------------------------
__global__ __launch_bounds__(256) void gemm_one(GemmDesc d)
{
    __shared__ ushort As[16384];
    __shared__ ushort Bs[16384];
    run_gemm(d, blockIdx.x, As, Bs);
}

__global__ __launch_bounds__(256) void gemm_dual(GemmDesc d0, int n0, GemmDesc d1)
{
    __shared__ ushort As[16384];
    __shared__ ushort Bs[16384];
    int f = blockIdx.x;
    if (f < n0) run_gemm(d0, f, As, Bs);
    else        run_gemm(d1, f - n0, As, Bs);
}

// reduce4 xp2 S=2 (blocks [0,1024)) || div_rows (blocks [1024,3024))
// aux||aux small-LDS fusion (proven pattern: aggred/auxdual2).
__global__ __launch_bounds__(256) void reddiv(
    const float* __restrict__ part, ushort* __restrict__ outs,
    const float* __restrict__ divc, float* __restrict__ loss, float scale)
{
    __shared__ float v[256];
    __shared__ float r2[256];
    int b = blockIdx.x, t = threadIdx.x;
    if (b < 1024) {
        reduce4_body(part, outs, (long)b * 256 + t, 2);
        return;
    }
    int i = b - 1024;
    float a = divc[(long)i * 512 + t], bb = divc[(long)i * 512 + 256 + t];
    v[t] = a * a;
    r2[t] = bb * bb;
    __syncthreads();
    for (int s = 128; s > 0; s >>= 1) {
        if (t < s) { v[t] += v[t + s]; r2[t] += r2[t + s]; }
        __syncthreads();
    }
    float na = fmaxf(sqrtf(v[0]), 1e-12f);
    float nb = fmaxf(sqrtf(r2[0]), 1e-12f);
    __syncthreads();
    float d = a / na - bb / nb;
    v[t] = d * d;
    __syncthreads();
    for (int s = 128; s > 0; s >>= 1) {
        if (t < s) v[t] += v[t + s];
        __syncthreads();
    }
    if (t == 0) atomicAdd(loss, v[0] * scale);
}

// csr_agg1 (blocks [0,2048)) + reduce4 xp1 S=4 (blocks [2048,3072))
__global__ __launch_bounds__(256) void aggred(
    const float* __restrict__ h, const int* __restrict__ ell,
    const int* __restrict__ cnt, ushort* __restrict__ a1,
    const float* __restrict__ part, ushort* __restrict__ outs)
{
    __shared__ float pl[4][256];
    int b = blockIdx.x, t = threadIdx.x;
    if (b >= 2048) {
        reduce4_body(part, outs, (long)(b - 2048) * 256 + t, 4);
        return;
    }
    int d = b;
    int w = t >> 6, lane = t & 63;
    int k = (d < 2000) ? min(cnt[d], 64) : 0;
    f32x4 s = {0.f, 0.f, 0.f, 0.f};
    int co = lane * 4;
    int j = w;
    for (; j + 12 < k; j += 16) {
        int e0 = ell[d + 2000 * j],        e1 = ell[d + 2000 * (j + 4)];
        int e2 = ell[d + 2000 * (j + 8)],  e3 = ell[d + 2000 * (j + 12)];
        f32x4 v0 = *(const f32x4*)&h[(long)e0 * 256 + co];
        f32x4 v1 = *(const f32x4*)&h[(long)e1 * 256 + co];
        f32x4 v2 = *(const f32x4*)&h[(long)e2 * 256 + co];
        f32x4 v3 = *(const f32x4*)&h[(long)e3 * 256 + co];
        s += v0; s += v1; s += v2; s += v3;
    }
    for (; j < k; j += 4)
        s += *(const f32x4*)&h[(long)ell[d + 2000 * j] * 256 + co];
#pragma unroll
    for (int q = 0; q < 4; ++q) pl[w][co + q] = s[q];
    __syncthreads();
    float inv = 1.f / fmaxf((float)k, 1.f);
    float a = (pl[0][t] + pl[1][t] + pl[2][t] + pl[3][t]) * inv;
    ushort hi = bf16_rne(a);
    long ro = (long)d * 1024;
    a1[ro + 512 + t] = hi;
    a1[ro + 768 + t] = bf16_rne(a - bf16_f32(hi));
}

// ---------------------------------------------------------------------------
// prep megakernel + fused ELL build (cnt pre-zeroed by memset).
// ---------------------------------------------------------------------------
__global__ __launch_bounds__(256) void prep(
    const float* __restrict__ ppr, const float* __restrict__ x,
    const float* __restrict__ Wr0, const float* __restrict__ Wl0,
    const float* __restrict__ Wr1, const float* __restrict__ Wl1,
    const float* __restrict__ W1,  const float* __restrict__ W2,
    const float* __restrict__ Wa,  const float* __restrict__ Wb,
    const float* __restrict__ Wp1, const float* __restrict__ Wp2,
    const int* __restrict__ src0, const int* __restrict__ dst0,
    const int* __restrict__ src1, const int* __restrict__ dst1,
    int E0, int E1,
    ushort* __restrict__ uws, int* __restrict__ iws, float* __restrict__ outloss)
{
    __shared__ float tsm[32][33];
    int b = blockIdx.x, t = threadIdx.x;
    int nEll = (E0 + E1 + 255) >> 8;

    if (b < nEll) {                         // ---- ELL bucket build ----
        int e = b * 256 + t;
        if (e < E0) {
            int d = dst0[e];
            int r = atomicAdd(&iws[ZCNT0 + d], 1);
            if (r < 64) iws[ELL0 + d + 8000 * r] = src0[e];
        } else if (e < E0 + E1) {
            int e1 = e - E0;
            int d = dst1[e1];
            int r = atomicAdd(&iws[ZCNT1 + d], 1);
            if (r < 64) iws[ELL1 + d + 2000 * r] = src1[e1];
        }
        return;
    }
    int b1 = b - nEll;
    if (b1 == 0) {                          // ---- zero loss ----
        if (t == 0) outloss[0] = 0.f;
        return;
    }
    b1 -= 1;
    if (b1 < 256) {                         // ---- pack weights ----
        int b2 = b1;
        int sec = b2 >> 5;
        const float *sa, *sb = nullptr; long dstoff; int N, KA, dA, KB = 0, dB = 0;
        switch (sec) {
            case 0: sa = Wr0; KA = 512; dA = 1; sb = Wl0; KB = 512; dB = 2;
                    dstoff = U_WC0; N = 256; break;
            case 1: sa = Wr1; KA = 256; dA = 2; sb = Wl1; KB = 256; dB = 2;
                    dstoff = U_WC1; N = 256; break;
            case 2: sa = W1;  KA = 256; dA = 2; dstoff = U_BD;          N = 256; break;
            case 3: sa = W2;  KA = 256; dA = 2; dstoff = U_BD + 131072; N = 256; break;
            case 4: sa = Wa;  KA = 512; dA = 2; dstoff = U_WAD;  N = 512; break;
            case 5: sa = Wb;  KA = 512; dA = 2; dstoff = U_WBD;  N = 256; break;
            case 6: sa = Wp1; KA = 256; dA = 2; dstoff = U_WP1D; N = 256; break;
            default: sa = Wp2; KA = 256; dA = 2; dstoff = U_WP2D; N = 256; break;
        }
        int kd = KA * dA + KB * dB;
        long totv = (long)N * kd / 2;
        for (long v = (long)(b2 & 31) * 256 + t; v < totv; v += 8192) {
            long idx = v * 2;
            int n = (int)(idx / kd), rem = (int)(idx % kd);
            f32x2 val;
            if (rem < KA * dA) {
                int sc = rem % KA;
                val = *(const f32x2*)&sa[(long)n * KA + sc];
            } else {
                int sc = (rem - KA * dA) % KB;
                val = *(const f32x2*)&sb[(long)n * KB + sc];
            }
            us2 o; o[0] = bf16_rne(val[0]); o[1] = bf16_rne(val[1]);
            *(us2*)&uws[dstoff + idx] = o;
        }
        return;
    }
    b1 -= 256;
    if (b1 < 8192) {                        // ---- ppr conversion ----
        int r = b1 >> 2, q = b1 & 3;
        bool live = r < 2000;
        const float* row = ppr + (long)r * 8000;
        int cbeg = q * 2048;
#pragma unroll
        for (int pass = 0; pass < 2; ++pass) {
            int c = cbeg + pass * 1024 + t * 4;
            f32x4 v = {0.f, 0.f, 0.f, 0.f};
            if (live && c < 8000) v = *(const f32x4*)(row + c);
            us4 u;
            u[0] = bf16_rne(v[0]); u[1] = bf16_rne(v[1]);
            u[2] = bf16_rne(v[2]); u[3] = bf16_rne(v[3]);
            *(us4*)&uws[U_PPRB + (long)r * 8192 + c] = u;
            if (c < 2048) {
                us4 w = u;
                if (c >= 2000) { w[0] = 0; w[1] = 0; w[2] = 0; w[3] = 0; }
                *(us4*)&uws[U_PPR2B + (long)r * 2048 + c] = w;
            }
        }
        return;
    }
    b1 -= 8192;
    if (b1 < 4096) {                        // ---- transpose x -> XTB ----
        int c0 = (b1 & 15) * 32, r0 = (b1 >> 4) * 32;
        int tx = t & 31, ty = t >> 5;
#pragma unroll
        for (int k = 0; k < 32; k += 8) {
            int r = r0 + ty + k;
            tsm[ty + k][tx] = (r < 8000) ? x[(long)r * 512 + c0 + tx] : 0.f;
        }
        __syncthreads();
#pragma unroll
        for (int k = 0; k < 32; k += 8) {
            int c = c0 + ty + k;
            uws[U_XTB + (long)c * 8192 + r0 + tx] = bf16_rne(tsm[tx][ty + k]);
        }
        return;
    }
    b1 -= 4096;
    {                                       // ---- x row pass -> XB + A0 ----
        long vi = (long)b1 * 256 + t;
        for (; vi < 5120000; vi += 327680) {
            long gidx = vi * 4;
            f32x4 v = *(const f32x4*)&x[gidx];
            us4 u;
            u[0] = bf16_rne(v[0]); u[1] = bf16_rne(v[1]);
            u[2] = bf16_rne(v[2]); u[3] = bf16_rne(v[3]);
            *(us4*)&uws[U_XB + gidx] = u;
            long row = gidx >> 9;
            if (row < 8064) {
                int col = (int)(gidx & 511);
                *(us4*)&uws[U_A0 + row * 1536 + col] = u;
            }
        }
    }
}

// ---------------------------------------------------------------------------
// layer-0 gather-mean from bf16 XB, ELL layout
// ---------------------------------------------------------------------------
__global__ __launch_bounds__(256) void csr_agg0(
    const ushort* __restrict__ xb, const int* __restrict__ ell,
    const int* __restrict__ cnt, ushort* __restrict__ a0)
{
    __shared__ float part[4][512];
    int d = blockIdx.x, t = threadIdx.x;
    int w = t >> 6, lane = t & 63;
    int k = (d < 8000) ? min(cnt[d], 64) : 0;
    float s[8] = {0.f, 0.f, 0.f, 0.f, 0.f, 0.f, 0.f, 0.f};
    int co = lane * 8;
    int j = w;
    for (; j + 12 < k; j += 16) {
        int e0 = ell[d + 8000 * j],        e1 = ell[d + 8000 * (j + 4)];
        int e2 = ell[d + 8000 * (j + 8)],  e3 = ell[d + 8000 * (j + 12)];
        us8 v0 = *(const us8*)&xb[(long)e0 * 512 + co];
        us8 v1 = *(const us8*)&xb[(long)e1 * 512 + co];
        us8 v2 = *(const us8*)&xb[(long)e2 * 512 + co];
        us8 v3 = *(const us8*)&xb[(long)e3 * 512 + co];
#pragma unroll
        for (int q = 0; q < 8; ++q)
            s[q] += bf16_f32(v0[q]) + bf16_f32(v1[q]) +
                    bf16_f32(v2[q]) + bf16_f32(v3[q]);
    }
    for (; j < k; j += 4) {
        us8 v = *(const us8*)&xb[(long)ell[d + 8000 * j] * 512 + co];
#pragma unroll
        for (int q = 0; q < 8; ++q) s[q] += bf16_f32(v[q]);
    }
#pragma unroll
    for (int q = 0; q < 8; ++q) part[w][co + q] = s[q];
    __syncthreads();
    float inv = 1.f / fmaxf((float)k, 1.f);
    long ro = (long)d * 1536;
#pragma unroll
    for (int h = 0; h < 2; ++h) {
        int c = 2 * t + h;
        float a = (part[0][c] + part[1][c] + part[2][c] + part[3][c]) * inv;
        ushort hi = bf16_rne(a);
        a0[ro + 512 + c] = hi;
        a0[ro + 1024 + c] = bf16_rne(a - bf16_f32(hi));
    }
}

// rowcombo1: logsoftmax + l2n + splits on H2 -> ESPL, SPLT[0:2048)
__global__ __launch_bounds__(256) void rowcombo1(
    const float* __restrict__ h2, ushort* __restrict__ espl,
    ushort* __restrict__ splt)
{
    __shared__ float red[256];
    int i = blockIdx.x, t = threadIdx.x;
    float v = h2[(long)i * 256 + t];
    red[t] = v;
    __syncthreads();
    for (int s = 128; s > 0; s >>= 1) {
        if (t < s) red[t] = fmaxf(red[t], red[t + s]);
        __syncthreads();
    }
    float m = red[0];
    __syncthreads();
    float e = expf(v - m);
    red[t] = e;
    __syncthreads();
    for (int s = 128; s > 0; s >>= 1) {
        if (t < s) red[t] += red[t + s];
        __syncthreads();
    }
    float eb = v - (m + logf(red[0]));
    ushort hh = bf16_rne(eb);
    espl[(long)i * 512 + t] = hh;
    espl[(long)i * 512 + 256 + t] = bf16_rne(eb - bf16_f32(hh));
    __syncthreads();
    red[t] = eb * eb;
    __syncthreads();
    for (int s = 128; s > 0; s >>= 1) {
        if (t < s) red[t] += red[t + s];
        __syncthreads();
    }
    float g = eb / fmaxf(sqrtf(red[0]), 1e-12f);
    ushort gh = bf16_rne(g);
    splt[(long)i * 512 + t] = gh;
    splt[(long)i * 512 + 256 + t] = bf16_rne(g - bf16_f32(gh));
}

// rowcombo2: l2n+split on XPBF -> SPLT rows [2048..)
__global__ __launch_bounds__(256) void rowcombo2(
    const float* __restrict__ xpb, ushort* __restrict__ splt)
{
    __shared__ float red[256];
    int i = blockIdx.x, t = threadIdx.x;
    float v = xpb[(long)i * 256 + t];
    red[t] = v * v;
    __syncthreads();
    for (int s = 128; s > 0; s >>= 1) {
        if (t < s) red[t] += red[t + s];
        __syncthreads();
    }
    float g = v / fmaxf(sqrtf(red[0]), 1e-12f);
    ushort gh = bf16_rne(g);
    long ro = (long)(2048 + i) * 512;
    splt[ro + t] = gh;
    splt[ro + 256 + t] = bf16_rne(g - bf16_f32(gh));
}

// ---------------------------------------------------------------------------
// final_clf: 4096 blocks, clf only (div_rows moved into reddiv).
// ---------------------------------------------------------------------------
__global__ __launch_bounds__(256) void final_clf(
    const float* __restrict__ p, const float* __restrict__ Wc1,
    const float* __restrict__ bc1, const float* __restrict__ Wc2,
    const float* __restrict__ bc2, float* __restrict__ out)
{
    __shared__ float v[256];
    __shared__ float ps[8][33];
    __shared__ float hsum[32];
    int b = blockIdx.x, t = threadIdx.x;
    int half = b >> 11, i = b & 2047;
    if (i >= 2000) return;
    v[t] = p[(long)b * 256 + t];
    __syncthreads();
    int o = t & 31, ch = t >> 5;
    const float* w = Wc1 + (long)o * 256 + ch * 32;
    const float* vv = v + ch * 32;
    float s = 0.f;
#pragma unroll
    for (int k2 = 0; k2 < 32; ++k2) s += vv[k2] * w[k2];
    ps[ch][o] = s;
    __syncthreads();
    if (t < 32) {
        float a = bc1[t];
#pragma unroll
        for (int c = 0; c < 8; ++c) a += ps[c][t];
        a = fmaxf(a, 0.f);
        hsum[t] = a * Wc2[t];
    }
    __syncthreads();
    if (t == 0) {
        float s2 = bc2[0];
        for (int k2 = 0; k2 < 32; ++k2) s2 += hsum[k2];
        out[(long)i * 2 + half] = s2;
    }
}

// ---------------------------------------------------------------------------
extern "C" void kernel_launch(void* const* d_in, const int* in_sizes, int n_in,
                              void* d_out, int out_size, void* d_ws, size_t ws_size,
                              hipStream_t stream)
{
    constexpr int N2 = 2000;

    const float* x   = (const float*)d_in[0];
    const float* ppr = (const float*)d_in[1];
    const int* src0  = (const int*)d_in[2];
    const int* dst0  = (const int*)d_in[3];
    const int* src1  = (const int*)d_in[4];
    const int* dst1  = (const int*)d_in[5];
    const float* Wl0 = (const float*)d_in[8];
    const float* bl0 = (const float*)d_in[9];
    const float* Wr0 = (const float*)d_in[10];
    const float* Wl1 = (const float*)d_in[11];
    const float* bl1 = (const float*)d_in[12];
    const float* Wr1 = (const float*)d_in[13];
    const float* Wa  = (const float*)d_in[14];
    const float* ba  = (const float*)d_in[15];
    const float* Wb  = (const float*)d_in[16];
    const float* bb  = (const float*)d_in[17];
    const float* W1  = (const float*)d_in[18];
    const float* W2  = (const float*)d_in[19];
    const float* Wp1 = (const float*)d_in[20];
    const float* bp1 = (const float*)d_in[21];
    const float* Wp2 = (const float*)d_in[22];
    const float* bp2 = (const float*)d_in[23];
    const float* Wc1 = (const float*)d_in[24];
    const float* bc1 = (const float*)d_in[25];
    const float* Wc2 = (const float*)d_in[26];
    const float* bc2 = (const float*)d_in[27];

    const int E0 = in_sizes[2];
    const int E1 = in_sizes[4];

    float* out = (float*)d_out;              // [2000,2] logits + [1] loss
    float* ws  = (float*)d_ws;
    int*   iws = (int*)d_ws;
    ushort* uws = (ushort*)((char*)d_ws + FEND * sizeof(float));

    GemmDesc z{};

    // 0. zero ELL counters (stream-ordered before prep)
    hipMemsetAsync(iws, 0, 10240 * sizeof(int), stream);

    // 1. prep + ELL build
    int nEll = (E0 + E1 + 255) / 256;
    int prepGrid = nEll + 1 + 256 + 8192 + 4096 + 1280;
    prep<<<prepGrid, 256, 0, stream>>>(ppr, x, Wr0, Wl0, Wr1, Wl1, W1, W2,
                                       Wa, Wb, Wp1, Wp2,
                                       src0, dst0, src1, dst1, E0, E1,
                                       uws, iws, out + (long)N2 * 2);

    // 2. layer-0 gather-mean
    csr_agg0<<<8064, 256, 0, stream>>>(uws + U_XB, iws + ELL0, iws + ZCNT0,
                                       uws + U_A0);

    // 3. xp1 split-K (256) || H1 (126)
    GemmDesc dxp1 = z;
    dxp1.A = uws + U_PPRB; dxp1.B = uws + U_XTB; dxp1.Cf = ws + PART;
    dxp1.K = 8192; dxp1.lda = 8192; dxp1.ldb = 8192; dxp1.ldc = 512;
    dxp1.gx = 4; dxp1.gy = 16; dxp1.kchunk = 2048; dxp1.slabsize = 1048576;
    dxp1.flags = 16 | 8;
    GemmDesc dh1 = z;
    dh1.A = uws + U_A0; dh1.B = uws + U_WC0; dh1.Cf = ws + H1F;
    dh1.Cs = uws + U_A1; dh1.bias = bl0;
    dh1.K = 1536; dh1.lda = 1536; dh1.ldb = 1536; dh1.ldc = 256;
    dh1.ldso = 1024; dh1.nsplit = 256; dh1.msplit = 2048;
    dh1.gx = 2; dh1.gy = 63; dh1.kchunk = 1536; dh1.flags = 3;
    gemm_dual<<<382, 256, 0, stream>>>(dxp1, 256, dh1);

    // 4. csr_agg1 (2048) || reduce4 xp1 (1024)
    aggred<<<3072, 256, 0, stream>>>(ws + H1F, iws + ELL1, iws + ZCNT1,
                                     uws + U_A1, ws + PART, uws + U_XPS);

    // 5. xpa (64) || H2 (32)
    GemmDesc dxpa = z;
    dxpa.A = uws + U_XPS; dxpa.B = uws + U_WAD; dxpa.Ct = uws + U_XPATB;
    dxpa.bias = ba;
    dxpa.K = 1024; dxpa.lda = 1024; dxpa.ldb = 1024; dxpa.ldt = 2048;
    dxpa.gx = 4; dxpa.gy = 16; dxpa.kchunk = 1024; dxpa.flags = 1 | 4 | 8;
    GemmDesc dh2 = z;
    dh2.A = uws + U_A1; dh2.B = uws + U_WC1; dh2.Cf = ws + H2F; dh2.bias = bl1;
    dh2.K = 1024; dh2.lda = 1024; dh2.ldb = 1024; dh2.ldc = 256;
    dh2.gx = 2; dh2.gy = 16; dh2.kchunk = 1024; dh2.flags = 8;
    gemm_dual<<<96, 256, 0, stream>>>(dxpa, 64, dh2);

    // 6. rowcombo1 standalone (full occupancy)
    rowcombo1<<<N2, 256, 0, stream>>>(ws + H2F, uws + U_ESPL, uws + U_SPLT);

    // 7. xp2 split-K (128) || div GEMM (64)
    GemmDesc dxp2 = z;
    dxp2.A = uws + U_PPR2B; dxp2.B = uws + U_XPATB; dxp2.Cf = ws + PART;
    dxp2.K = 2048; dxp2.lda = 2048; dxp2.ldb = 2048; dxp2.ldc = 512;
    dxp2.gx = 4; dxp2.gy = 16; dxp2.kchunk = 1024; dxp2.slabsize = 1048576;
    dxp2.flags = 16 | 8;
    GemmDesc ddiv = z;
    ddiv.A = uws + U_ESPL; ddiv.B = uws + U_BD; ddiv.Cf = ws + DIVCF;
    ddiv.K = 512; ddiv.lda = 512; ddiv.ldb = 512; ddiv.ldc = 512;
    ddiv.gx = 4; ddiv.gy = 16; ddiv.kchunk = 512; ddiv.flags = 8;
    gemm_dual<<<192, 256, 0, stream>>>(dxp2, 128, ddiv);

    // 8. reduce4 xp2 (1024) || div_rows (2000) -> out[4000]
    reddiv<<<3024, 256, 0, stream>>>(ws + PART, uws + U_XPS,
                                     ws + DIVCF, out + (long)N2 * 2, 1.0f / N2);

    // 9. xpb (32)
    GemmDesc dxpb = z;
    dxpb.A = uws + U_XPS; dxpb.B = uws + U_WBD; dxpb.Cf = ws + XPBF;
    dxpb.bias = bb;
    dxpb.K = 1024; dxpb.lda = 1024; dxpb.ldb = 1024; dxpb.ldc = 256;
    dxpb.gx = 2; dxpb.gy = 16; dxpb.kchunk = 1024; dxpb.flags = 8;
    gemm_one<<<32, 256, 0, stream>>>(dxpb);

    // 10. rowcombo2: l2n(xpb) -> SPLT rows [2048..)
    rowcombo2<<<N2, 256, 0, stream>>>(ws + XPBF, uws + U_SPLT);

    // 11. proj1 (64)
    GemmDesc dp1 = z;
    dp1.A = uws + U_SPLT; dp1.B = uws + U_WP1D; dp1.Cs = uws + U_TSPL;
    dp1.bias = bp1;
    dp1.K = 512; dp1.lda = 512; dp1.ldb = 512;
    dp1.ldso = 512; dp1.nsplit = 256; dp1.msplit = 4096;
    dp1.gx = 2; dp1.gy = 32; dp1.kchunk = 512; dp1.flags = 1 | 2 | 8;
    gemm_one<<<64, 256, 0, stream>>>(dp1);

    // 12. proj2 (64)
    GemmDesc dp2 = z;
    dp2.A = uws + U_TSPL; dp2.B = uws + U_WP2D; dp2.Cf = ws + PB2;
    dp2.bias = bp2;
    dp2.K = 512; dp2.lda = 512; dp2.ldb = 512; dp2.ldc = 256;
    dp2.gx = 2; dp2.gy = 32; dp2.kchunk = 512; dp2.flags = 8;
    gemm_one<<<64, 256, 0, stream>>>(dp2);

    // 13. clf -> out logits
    final_clf<<<4096, 256, 0, stream>>>(ws + PB2, Wc1, bc1, Wc2, bc2, out);
}